// Round 1
// baseline (804.155 us; speedup 1.0000x reference)
//
#include <hip/hip_runtime.h>

// MiniSelfAttention: B=8, T=2048, D=1024, fp32 in/out, fp16 MFMA internally.
//
// Pipeline (all NT GEMMs: C[M,N] = A[M,K] @ B[N,K]^T, K-contiguous operands):
//   WqT/WkT/WvT/WpT = cast_transpose(W)            (fp16 [dout,din])
//   q = (x @ Wq) * 1/32   (fp16)                   [16384,1024]
//   k =  x @ Wk           (fp16)                   [16384,1024]
//   vT = (x @ Wv)^T       (fp16, [8][1024][2048])  transposed store
//   per batch-pair p (S buffer reused, 32MB fp32):
//     S = q@k^T (fp32) ; softmax rows (fp32, in-place) ; ctx = P@vT^T (fp16)
//     ctx overwrites q's region (q dead after S)
//   out = ctx @ Wp + bp   (fp32) -> d_out
//
// ws layout (136 MB total):
//   [0,8)MB   WqT,WkT,WvT,WpT (2MB each)
//   [8,40)    q fp16 (later ctx)
//   [40,72)   k fp16
//   [72,104)  vT fp16
//   [104,136) S fp32 [2][2048][2048]

typedef _Float16 half_t;
typedef _Float16 half8 __attribute__((ext_vector_type(8)));
typedef float floatx4 __attribute__((ext_vector_type(4)));

#define LDSS 40  // LDS row stride in halves: 32 + 8 pad, 80B (16B-aligned, 2-way bank alias = free)

template<bool AF32, bool OUTF32, bool TSTORE, bool BIAS>
__global__ __launch_bounds__(256, 2)
void gemm_nt(const void* __restrict__ Av, const half_t* __restrict__ B,
             void* __restrict__ Cv, const float* __restrict__ bias,
             int K, int lda, int ldb, int ldc,
             long long bsA, long long bsB, long long bsC, float alpha)
{
    __shared__ half_t As[128 * LDSS];
    __shared__ half_t Bs[128 * LDSS];

    const int tid  = threadIdx.x;
    const int lane = tid & 63;
    const int wid  = tid >> 6;
    const int wr   = (wid >> 1) * 64;   // wave row offset in 128x128 tile
    const int wc   = (wid & 1) * 64;    // wave col offset
    const long long z = blockIdx.z;
    const int rowBase = blockIdx.y * 128;
    const int colBase = blockIdx.x * 128;

    // staging: each thread handles rows r0 and r0+64, one 8-half chunk at kc
    const int r0 = tid >> 2;        // 0..63
    const int kc = (tid & 3) * 8;   // 0,8,16,24

    const half_t* Bp = B + z * bsB + (long long)colBase * ldb;
    const float*  Af = (const float*)Av;
    const half_t* Ah = (const half_t*)Av;
    const long long aBase = z * bsA + (long long)rowBase * lda;

    floatx4 acc[4][4];
    #pragma unroll
    for (int m = 0; m < 4; ++m)
        #pragma unroll
        for (int n = 0; n < 4; ++n)
            #pragma unroll
            for (int j = 0; j < 4; ++j) acc[m][n][j] = 0.0f;

    for (int kk = 0; kk < K; kk += 32) {
        half8 a0, a1, b0, b1;
        if (AF32) {
            const float* p0 = Af + aBase + (long long)r0 * lda + kk + kc;
            const float* p1 = Af + aBase + (long long)(r0 + 64) * lda + kk + kc;
            floatx4 f00 = *(const floatx4*)p0;
            floatx4 f01 = *(const floatx4*)(p0 + 4);
            floatx4 f10 = *(const floatx4*)p1;
            floatx4 f11 = *(const floatx4*)(p1 + 4);
            #pragma unroll
            for (int j = 0; j < 4; ++j) {
                a0[j]     = (half_t)f00[j];
                a0[j + 4] = (half_t)f01[j];
                a1[j]     = (half_t)f10[j];
                a1[j + 4] = (half_t)f11[j];
            }
        } else {
            a0 = *(const half8*)(Ah + aBase + (long long)r0 * lda + kk + kc);
            a1 = *(const half8*)(Ah + aBase + (long long)(r0 + 64) * lda + kk + kc);
        }
        b0 = *(const half8*)(Bp + (long long)r0 * ldb + kk + kc);
        b1 = *(const half8*)(Bp + (long long)(r0 + 64) * ldb + kk + kc);

        __syncthreads();  // previous iter's frag reads done
        *(half8*)&As[r0 * LDSS + kc]        = a0;
        *(half8*)&As[(r0 + 64) * LDSS + kc] = a1;
        *(half8*)&Bs[r0 * LDSS + kc]        = b0;
        *(half8*)&Bs[(r0 + 64) * LDSS + kc] = b1;
        __syncthreads();

        const int fr = lane & 15;        // frag row/col within 16
        const int fk = (lane >> 4) * 8;  // frag K offset (A/B lane layout: [m|n=lane&15][k=quad*8+j])
        half8 af[4], bf[4];
        #pragma unroll
        for (int m = 0; m < 4; ++m)
            af[m] = *(const half8*)&As[(wr + m * 16 + fr) * LDSS + fk];
        #pragma unroll
        for (int n = 0; n < 4; ++n)
            bf[n] = *(const half8*)&Bs[(wc + n * 16 + fr) * LDSS + fk];
        #pragma unroll
        for (int m = 0; m < 4; ++m)
            #pragma unroll
            for (int n = 0; n < 4; ++n)
                acc[m][n] = __builtin_amdgcn_mfma_f32_16x16x32_f16(af[m], bf[n], acc[m][n], 0, 0, 0);
    }

    // epilogue: C/D layout col=lane&15, row=(lane>>4)*4+reg (gfx950-verified)
    const int ecol = lane & 15;
    const int q4   = (lane >> 4) * 4;
    #pragma unroll
    for (int m = 0; m < 4; ++m) {
        #pragma unroll
        for (int n = 0; n < 4; ++n) {
            const int gcol = colBase + wc + n * 16 + ecol;
            #pragma unroll
            for (int r = 0; r < 4; ++r) {
                const int grow = rowBase + wr + m * 16 + q4 + r;
                float v = acc[m][n][r] * alpha;
                if (BIAS) v += bias[gcol];
                if (TSTORE) {
                    // v projection: write vT[b][gcol][t], b=grow>>11, t=grow&2047
                    const long long bb = grow >> 11;
                    const long long tt = grow & 2047;
                    ((half_t*)Cv)[bb * bsC + (long long)gcol * ldc + tt] = (half_t)v;
                } else {
                    const long long idx = z * bsC + (long long)grow * ldc + gcol;
                    if (OUTF32) ((float*)Cv)[idx] = v;
                    else        ((half_t*)Cv)[idx] = (half_t)v;
                }
            }
        }
    }
}

// 1024x1024 fp32 -> fp16 transposed
__global__ __launch_bounds__(256)
void cast_transpose(const float* __restrict__ W, half_t* __restrict__ WT)
{
    __shared__ float t[32][33];
    const int bx = blockIdx.x * 32, by = blockIdx.y * 32;
    const int tx = threadIdx.x, ty = threadIdx.y;
    #pragma unroll
    for (int i = 0; i < 32; i += 8)
        t[ty + i][tx] = W[(long long)(by + ty + i) * 1024 + bx + tx];
    __syncthreads();
    #pragma unroll
    for (int i = 0; i < 32; i += 8)
        WT[(long long)(bx + ty + i) * 1024 + by + tx] = (half_t)t[tx][ty + i];
}

// in-place row softmax over 2048 fp32, one block (256 thr) per row
__global__ __launch_bounds__(256)
void softmax_rows(float* __restrict__ S)
{
    const long long base = (long long)blockIdx.x * 2048;
    const int t = threadIdx.x;
    float v[8];
    #pragma unroll
    for (int i = 0; i < 8; ++i) v[i] = S[base + i * 256 + t];
    float m = -3.0e38f;
    #pragma unroll
    for (int i = 0; i < 8; ++i) m = fmaxf(m, v[i]);
    #pragma unroll
    for (int off = 32; off > 0; off >>= 1) m = fmaxf(m, __shfl_down(m, off));
    __shared__ float redm[4], reds[4];
    const int lane = t & 63, wid = t >> 6;
    if (lane == 0) redm[wid] = m;
    __syncthreads();
    const float M = fmaxf(fmaxf(redm[0], redm[1]), fmaxf(redm[2], redm[3]));
    float s = 0.f;
    #pragma unroll
    for (int i = 0; i < 8; ++i) { v[i] = __expf(v[i] - M); s += v[i]; }
    #pragma unroll
    for (int off = 32; off > 0; off >>= 1) s += __shfl_down(s, off);
    if (lane == 0) reds[wid] = s;
    __syncthreads();
    const float inv = 1.0f / (reds[0] + reds[1] + reds[2] + reds[3]);
    #pragma unroll
    for (int i = 0; i < 8; ++i) S[base + i * 256 + t] = v[i] * inv;
}

extern "C" void kernel_launch(void* const* d_in, const int* in_sizes, int n_in,
                              void* d_out, int out_size, void* d_ws, size_t ws_size,
                              hipStream_t stream)
{
    const float* x  = (const float*)d_in[0];
    const float* Wq = (const float*)d_in[1];
    const float* Wk = (const float*)d_in[2];
    const float* Wv = (const float*)d_in[3];
    const float* Wp = (const float*)d_in[4];
    const float* bp = (const float*)d_in[5];
    float* out = (float*)d_out;

    char* ws = (char*)d_ws;
    const long long MB = 1024LL * 1024LL;
    half_t* WqT = (half_t*)(ws + 0 * MB);
    half_t* WkT = (half_t*)(ws + 2 * MB);
    half_t* WvT = (half_t*)(ws + 4 * MB);
    half_t* WpT = (half_t*)(ws + 6 * MB);
    half_t* q   = (half_t*)(ws + 8 * MB);    // 32 MB, later reused as ctx
    half_t* k   = (half_t*)(ws + 40 * MB);   // 32 MB
    half_t* vT  = (half_t*)(ws + 72 * MB);   // 32 MB, [8][1024][2048]
    float*  S   = (float*)(ws + 104 * MB);   // 32 MB, [2][2048][2048] fp32

    dim3 tb(32, 8);
    dim3 tg(32, 32);
    cast_transpose<<<tg, tb, 0, stream>>>(Wq, WqT);
    cast_transpose<<<tg, tb, 0, stream>>>(Wk, WkT);
    cast_transpose<<<tg, tb, 0, stream>>>(Wv, WvT);
    cast_transpose<<<tg, tb, 0, stream>>>(Wp, WpT);

    dim3 blk(256);
    // q = (x @ Wq) * 1/sqrt(D)  (scale folded here), k, vT
    gemm_nt<true,  false, false, false><<<dim3(8, 128, 1), blk, 0, stream>>>(
        x, WqT, q, nullptr, 1024, 1024, 1024, 1024, 0, 0, 0, 0.03125f);
    gemm_nt<true,  false, false, false><<<dim3(8, 128, 1), blk, 0, stream>>>(
        x, WkT, k, nullptr, 1024, 1024, 1024, 1024, 0, 0, 0, 1.0f);
    gemm_nt<true,  false, true,  false><<<dim3(8, 128, 1), blk, 0, stream>>>(
        x, WvT, vT, nullptr, 1024, 1024, 1024, 2048, 0, 0, 2048LL * 1024, 1.0f);

    for (int p = 0; p < 4; ++p) {
        half_t* qp = q  + (long long)p * 2 * 2048 * 1024;
        half_t* kp = k  + (long long)p * 2 * 2048 * 1024;
        half_t* vp = vT + (long long)p * 2 * 2048 * 1024;
        half_t* cp = q  + (long long)p * 2 * 2048 * 1024;  // ctx overwrites dead q

        // S = q @ k^T (fp32 out)
        gemm_nt<false, true, false, false><<<dim3(16, 16, 2), blk, 0, stream>>>(
            qp, kp, S, nullptr, 1024, 1024, 1024, 2048,
            2048LL * 1024, 2048LL * 1024, 2048LL * 2048, 1.0f);
        // row softmax, in place, fp32
        softmax_rows<<<4096, blk, 0, stream>>>(S);
        // ctx = P @ vT^T (A = S fp32, cast in staging)
        gemm_nt<true, false, false, false><<<dim3(8, 16, 2), blk, 0, stream>>>(
            S, vp, cp, nullptr, 2048, 2048, 2048, 1024,
            2048LL * 2048, 1024LL * 2048, 2048LL * 1024, 1.0f);
    }

    // out = ctx @ Wp + bp (fp32)
    gemm_nt<false, true, false, true><<<dim3(8, 128, 1), blk, 0, stream>>>(
        q, WpT, out, bp, 1024, 1024, 1024, 1024, 0, 0, 0, 1.0f);
}

// Round 2
// 561.731 us; speedup vs baseline: 1.4316x; 1.4316x over previous
//
#include <hip/hip_runtime.h>

// MiniSelfAttention: B=8, T=2048, D=1024, fp32 in/out, fp16 MFMA internally.
// R2: m97-style GEMM — global_load_lds width-16, unpadded LDS, all-fp16 operands.
//
// Pipeline (all NT GEMMs: C[M,N] = A[M,K] @ B[N,K]^T, fp16 A/B, fp32 acc):
//   x16 = cast(x) fp16                       (reads x once)
//   WqT/WkT/WvT/WpT = cast_transpose(W) fp16
//   q = (x16 @ WqT^T) * 1/32  fp16 ; k = x16 @ WkT^T fp16 ; vT = (x16 @ WvT^T)^T fp16
//   per batch group g (ZB batches, ZB in {4,2,1} by ws_size):
//     S = q@k^T (fp32) ; softmax: P = softmax_rows(S) fp16 ; ctx = P@vT^T fp16 (overwrites q)
//   out = ctx @ WpT^T + bp  fp32 -> d_out
//
// ws layout (MB):
//   [0,8)    WqT,WkT,WvT,WvT (2MB each fp16)
//   [8,40)   q fp16 (later ctx)
//   [40,72)  k fp16
//   [72,104) vT fp16 [8][1024][2048]
//   [104,..) x16 fp16 32MB (dead after projections), then overlaid by:
//   [104, 104+ZB*16)          S fp32 [ZB][2048][2048]
//   [104+ZB*16, 104+ZB*24)    P fp16 [ZB][2048][2048]
// total: ZB=4 -> 200MB, ZB=2 -> 152MB, ZB=1 -> 128MB

typedef _Float16 half_t;
typedef _Float16 half8 __attribute__((ext_vector_type(8)));
typedef float floatx4 __attribute__((ext_vector_type(4)));

// async global->LDS, 16B per lane; LDS dest = wave-uniform base + lane*16
#define GLD16(gp, lp)                                                          \
    __builtin_amdgcn_global_load_lds(                                          \
        (const __attribute__((address_space(1))) void*)(gp),                   \
        (__attribute__((address_space(3))) void*)(lp), 16, 0, 0)

// ---------------------------------------------------------------------------
// m97-structure fp16 NT GEMM: 128x128 tile, BK=32, 4 waves, 4x4 16x16x32 frags
// ---------------------------------------------------------------------------
template<bool OUTF32, bool TSTORE, bool BIAS>
__global__ __launch_bounds__(256, 2)
void gemm16(const half_t* __restrict__ A, const half_t* __restrict__ B,
            void* __restrict__ Cv, const float* __restrict__ bias,
            int K, int lda, int ldb, int ldc,
            long long bsA, long long bsB, long long bsC, float alpha)
{
    __shared__ half_t As[128 * 32];  // unpadded: required by global_load_lds
    __shared__ half_t Bs[128 * 32];

    const int tid  = threadIdx.x;
    const int lane = tid & 63;
    const int wid  = tid >> 6;
    const int wr   = (wid >> 1) * 64;   // wave row offset in 128x128 tile
    const int wc   = (wid & 1) * 64;    // wave col offset
    const long long z = blockIdx.z;
    const int rowBase = blockIdx.y * 128;
    const int colBase = blockIdx.x * 128;

    // staging: wave w stages tile rows [w*32, w*32+32) of A and of B,
    // two 1KB instructions each (16 rows x 64B per instruction).
    const int srow = wid * 32 + (lane >> 2);   // this lane's first row
    const int scol = (lane & 3) * 8;           // halves offset within 64B row

    const half_t* ga0 = A + z * bsA + (long long)(rowBase + srow) * lda + scol;
    const half_t* ga1 = ga0 + 16LL * lda;
    const half_t* gb0 = B + z * bsB + (long long)(colBase + srow) * ldb + scol;
    const half_t* gb1 = gb0 + 16LL * ldb;
    half_t* la0 = &As[(wid * 32) * 32];        // wave-uniform LDS bases
    half_t* la1 = &As[(wid * 32 + 16) * 32];
    half_t* lb0 = &Bs[(wid * 32) * 32];
    half_t* lb1 = &Bs[(wid * 32 + 16) * 32];

    floatx4 acc[4][4];
    #pragma unroll
    for (int m = 0; m < 4; ++m)
        #pragma unroll
        for (int n = 0; n < 4; ++n)
            #pragma unroll
            for (int j = 0; j < 4; ++j) acc[m][n][j] = 0.0f;

    const int fr = lane & 15;        // frag row/col within 16
    const int fk = (lane >> 4) * 8;  // frag K offset

    for (int kk = 0; kk < K; kk += 32) {
        __syncthreads();             // prev iter's frag reads done
        GLD16(ga0 + kk, la0);
        GLD16(ga1 + kk, la1);
        GLD16(gb0 + kk, lb0);
        GLD16(gb1 + kk, lb1);
        __syncthreads();             // compiler drains vmcnt before s_barrier

        half8 af[4], bf[4];
        #pragma unroll
        for (int m = 0; m < 4; ++m)
            af[m] = *(const half8*)&As[(wr + m * 16 + fr) * 32 + fk];
        #pragma unroll
        for (int n = 0; n < 4; ++n)
            bf[n] = *(const half8*)&Bs[(wc + n * 16 + fr) * 32 + fk];
        #pragma unroll
        for (int m = 0; m < 4; ++m)
            #pragma unroll
            for (int n = 0; n < 4; ++n)
                acc[m][n] = __builtin_amdgcn_mfma_f32_16x16x32_f16(af[m], bf[n], acc[m][n], 0, 0, 0);
    }

    // epilogue: C/D layout col=lane&15, row=(lane>>4)*4+reg (gfx950-verified)
    const int ecol = lane & 15;
    const int q4   = (lane >> 4) * 4;
    #pragma unroll
    for (int m = 0; m < 4; ++m) {
        #pragma unroll
        for (int n = 0; n < 4; ++n) {
            const int gcol = colBase + wc + n * 16 + ecol;
            #pragma unroll
            for (int r = 0; r < 4; ++r) {
                const int grow = rowBase + wr + m * 16 + q4 + r;
                float v = acc[m][n][r] * alpha;
                if (BIAS) v += bias[gcol];
                if (TSTORE) {
                    // v projection: write vT[b][gcol][t], b=grow>>11, t=grow&2047
                    const long long bb = grow >> 11;
                    const long long tt = grow & 2047;
                    ((half_t*)Cv)[bb * bsC + (long long)gcol * ldc + tt] = (half_t)v;
                } else {
                    const long long idx = z * bsC + (long long)grow * ldc + gcol;
                    if (OUTF32) ((float*)Cv)[idx] = v;
                    else        ((half_t*)Cv)[idx] = (half_t)v;
                }
            }
        }
    }
}

// fp32 -> fp16 flat cast, 8 elems/thread
__global__ __launch_bounds__(256)
void cast16(const float* __restrict__ x, half_t* __restrict__ y)
{
    const long long i = ((long long)blockIdx.x * 256 + threadIdx.x) * 8;
    floatx4 a = *(const floatx4*)(x + i);
    floatx4 b = *(const floatx4*)(x + i + 4);
    half8 h;
    #pragma unroll
    for (int j = 0; j < 4; ++j) { h[j] = (half_t)a[j]; h[j + 4] = (half_t)b[j]; }
    *(half8*)(y + i) = h;
}

// 1024x1024 fp32 -> fp16 transposed
__global__ __launch_bounds__(256)
void cast_transpose(const float* __restrict__ W, half_t* __restrict__ WT)
{
    __shared__ float t[32][33];
    const int bx = blockIdx.x * 32, by = blockIdx.y * 32;
    const int tx = threadIdx.x, ty = threadIdx.y;
    #pragma unroll
    for (int i = 0; i < 32; i += 8)
        t[ty + i][tx] = W[(long long)(by + ty + i) * 1024 + bx + tx];
    __syncthreads();
    #pragma unroll
    for (int i = 0; i < 32; i += 8)
        WT[(long long)(bx + ty + i) * 1024 + by + tx] = (half_t)t[tx][ty + i];
}

// row softmax: read S fp32 row (2048), write P fp16 row; one 256-thr block/row
__global__ __launch_bounds__(256)
void softmax_rows(const float* __restrict__ S, half_t* __restrict__ P)
{
    const long long base = (long long)blockIdx.x * 2048;
    const int t = threadIdx.x;
    float v[8];
    #pragma unroll
    for (int i = 0; i < 8; ++i) v[i] = S[base + i * 256 + t];
    float m = -3.0e38f;
    #pragma unroll
    for (int i = 0; i < 8; ++i) m = fmaxf(m, v[i]);
    #pragma unroll
    for (int off = 32; off > 0; off >>= 1) m = fmaxf(m, __shfl_down(m, off));
    __shared__ float redm[4], reds[4];
    const int lane = t & 63, wid = t >> 6;
    if (lane == 0) redm[wid] = m;
    __syncthreads();
    const float M = fmaxf(fmaxf(redm[0], redm[1]), fmaxf(redm[2], redm[3]));
    float s = 0.f;
    #pragma unroll
    for (int i = 0; i < 8; ++i) { v[i] = __expf(v[i] - M); s += v[i]; }
    #pragma unroll
    for (int off = 32; off > 0; off >>= 1) s += __shfl_down(s, off);
    if (lane == 0) reds[wid] = s;
    __syncthreads();
    const float inv = 1.0f / (reds[0] + reds[1] + reds[2] + reds[3]);
    #pragma unroll
    for (int i = 0; i < 8; ++i) P[base + i * 256 + t] = (half_t)(v[i] * inv);
}

extern "C" void kernel_launch(void* const* d_in, const int* in_sizes, int n_in,
                              void* d_out, int out_size, void* d_ws, size_t ws_size,
                              hipStream_t stream)
{
    const float* x  = (const float*)d_in[0];
    const float* Wq = (const float*)d_in[1];
    const float* Wk = (const float*)d_in[2];
    const float* Wv = (const float*)d_in[3];
    const float* Wp = (const float*)d_in[4];
    const float* bp = (const float*)d_in[5];
    float* out = (float*)d_out;

    char* ws = (char*)d_ws;
    const long long MB = 1024LL * 1024LL;
    half_t* WqT = (half_t*)(ws + 0 * MB);
    half_t* WkT = (half_t*)(ws + 2 * MB);
    half_t* WvT = (half_t*)(ws + 4 * MB);
    half_t* WpT = (half_t*)(ws + 6 * MB);
    half_t* q   = (half_t*)(ws + 8 * MB);    // 32 MB, later reused as ctx
    half_t* k   = (half_t*)(ws + 40 * MB);   // 32 MB
    half_t* vT  = (half_t*)(ws + 72 * MB);   // 32 MB, [8][1024][2048]
    half_t* x16 = (half_t*)(ws + 104 * MB);  // 32 MB, dead after projections

    // batches per group, sized to workspace (constant across calls)
    const int ZB = (ws_size >= (size_t)(200 * MB)) ? 4
                 : (ws_size >= (size_t)(152 * MB)) ? 2 : 1;
    float*  S = (float*)(ws + 104 * MB);                    // [ZB][2048][2048] fp32 (overlays x16)
    half_t* P = (half_t*)(ws + (104 + ZB * 16) * MB);       // [ZB][2048][2048] fp16

    dim3 blk(256);
    cast16<<<8192, blk, 0, stream>>>(x, x16);
    dim3 tb(32, 8), tg(32, 32);
    cast_transpose<<<tg, tb, 0, stream>>>(Wq, WqT);
    cast_transpose<<<tg, tb, 0, stream>>>(Wk, WkT);
    cast_transpose<<<tg, tb, 0, stream>>>(Wv, WvT);
    cast_transpose<<<tg, tb, 0, stream>>>(Wp, WpT);

    // projections (scale 1/sqrt(1024)=1/32 folded into q)
    gemm16<false, false, false><<<dim3(8, 128, 1), blk, 0, stream>>>(
        x16, WqT, q, nullptr, 1024, 1024, 1024, 1024, 0, 0, 0, 0.03125f);
    gemm16<false, false, false><<<dim3(8, 128, 1), blk, 0, stream>>>(
        x16, WkT, k, nullptr, 1024, 1024, 1024, 1024, 0, 0, 0, 1.0f);
    gemm16<false, true,  false><<<dim3(8, 128, 1), blk, 0, stream>>>(
        x16, WvT, vT, nullptr, 1024, 1024, 1024, 2048, 0, 0, 2048LL * 1024, 1.0f);

    for (int g = 0; g < 8 / ZB; ++g) {
        const long long off = (long long)g * ZB * 2048 * 1024;
        half_t* qp = q  + off;
        half_t* kp = k  + off;
        half_t* vp = vT + off;
        half_t* cp = q  + off;   // ctx overwrites dead q

        // S = q @ k^T (fp32)
        gemm16<true, false, false><<<dim3(16, 16, ZB), blk, 0, stream>>>(
            qp, kp, S, nullptr, 1024, 1024, 1024, 2048,
            2048LL * 1024, 2048LL * 1024, 2048LL * 2048, 1.0f);
        // P = softmax(S) fp16
        softmax_rows<<<ZB * 2048, blk, 0, stream>>>(S, P);
        // ctx = P @ vT^T (fp16)
        gemm16<false, false, false><<<dim3(8, 16, ZB), blk, 0, stream>>>(
            P, vp, cp, nullptr, 2048, 2048, 2048, 1024,
            2048LL * 2048, 1024LL * 2048, 2048LL * 1024, 1.0f);
    }

    // out = ctx @ Wp + bp (fp32)
    gemm16<true, false, true><<<dim3(8, 128, 1), blk, 0, stream>>>(
        q, WpT, out, bp, 1024, 1024, 1024, 1024, 0, 0, 0, 1.0f);
}

// Round 3
// 555.013 us; speedup vs baseline: 1.4489x; 1.0121x over previous
//
#include <hip/hip_runtime.h>

// MiniSelfAttention: B=8, T=2048, D=1024, fp32 in/out, fp16 MFMA internally.
// R3: occupancy restructure — fused QKV (N=3072, 3072 blocks), single S-GEMM /
// softmax / PV over all 8 batches (ZB=8), S held fp16. m97 K-loop unchanged.
//
// ws layout (MB):
//   [0,6)    WqkvT = WqT|WkT|WvT contiguous (fp16 [3072][1024])
//   [6,8)    WpT fp16
//   [8,40)   q fp16 [8][2048][1024]   (later overwritten by ctx)
//   [40,72)  k fp16
//   [72,104) vT fp16 [8][1024][2048]
//   [104,136) x16 fp16 (dead after QKV), overlaid by:
//   [104,168) S fp16 [8][2048][2048]  (softmaxed in place -> P)
// total 168 MB (ws >= 200 MB confirmed by R2's ZB=4 path running)

typedef _Float16 half_t;
typedef _Float16 half8 __attribute__((ext_vector_type(8)));
typedef float floatx4 __attribute__((ext_vector_type(4)));

// async global->LDS, 16B per lane; LDS dest = wave-uniform base + lane*16
#define GLD16(gp, lp)                                                          \
    __builtin_amdgcn_global_load_lds(                                          \
        (const __attribute__((address_space(1))) void*)(gp),                   \
        (__attribute__((address_space(3))) void*)(lp), 16, 0, 0)

// ---------------------------------------------------------------------------
// m97-structure fp16 NT GEMM: 128x128 tile, BK=32, 4 waves, 4x4 16x16x32 frags
// EPI: 0 = fp16 C store; 1 = fp32 C + bias; 2 = QKV-routed (q*1/32, k, vT)
// ---------------------------------------------------------------------------
template<int EPI>
__global__ __launch_bounds__(256, 2)
void gemm16(const half_t* __restrict__ A, const half_t* __restrict__ B,
            void* __restrict__ Cv, void* __restrict__ C2, void* __restrict__ C3,
            const float* __restrict__ bias, int K, int lda, int ldb, int ldc,
            long long bsA, long long bsB, long long bsC)
{
    __shared__ half_t As[128 * 32];  // unpadded: required by global_load_lds
    __shared__ half_t Bs[128 * 32];

    const int tid  = threadIdx.x;
    const int lane = tid & 63;
    const int wid  = tid >> 6;
    const int wr   = (wid >> 1) * 64;
    const int wc   = (wid & 1) * 64;
    const long long z = blockIdx.z;
    const int rowBase = blockIdx.y * 128;
    const int colBase = blockIdx.x * 128;

    // staging: wave w stages tile rows [w*32, w*32+32) of A and B,
    // two 1KB global_load_lds each (16 rows x 64B per instruction)
    const int srow = wid * 32 + (lane >> 2);
    const int scol = (lane & 3) * 8;

    const half_t* ga0 = A + z * bsA + (long long)(rowBase + srow) * lda + scol;
    const half_t* ga1 = ga0 + 16LL * lda;
    const half_t* gb0 = B + z * bsB + (long long)(colBase + srow) * ldb + scol;
    const half_t* gb1 = gb0 + 16LL * ldb;
    half_t* la0 = &As[(wid * 32) * 32];
    half_t* la1 = &As[(wid * 32 + 16) * 32];
    half_t* lb0 = &Bs[(wid * 32) * 32];
    half_t* lb1 = &Bs[(wid * 32 + 16) * 32];

    floatx4 acc[4][4];
    #pragma unroll
    for (int m = 0; m < 4; ++m)
        #pragma unroll
        for (int n = 0; n < 4; ++n)
            #pragma unroll
            for (int j = 0; j < 4; ++j) acc[m][n][j] = 0.0f;

    const int fr = lane & 15;
    const int fk = (lane >> 4) * 8;

    for (int kk = 0; kk < K; kk += 32) {
        __syncthreads();
        GLD16(ga0 + kk, la0);
        GLD16(ga1 + kk, la1);
        GLD16(gb0 + kk, lb0);
        GLD16(gb1 + kk, lb1);
        __syncthreads();

        half8 af[4], bf[4];
        #pragma unroll
        for (int m = 0; m < 4; ++m)
            af[m] = *(const half8*)&As[(wr + m * 16 + fr) * 32 + fk];
        #pragma unroll
        for (int n = 0; n < 4; ++n)
            bf[n] = *(const half8*)&Bs[(wc + n * 16 + fr) * 32 + fk];
        #pragma unroll
        for (int m = 0; m < 4; ++m)
            #pragma unroll
            for (int n = 0; n < 4; ++n)
                acc[m][n] = __builtin_amdgcn_mfma_f32_16x16x32_f16(af[m], bf[n], acc[m][n], 0, 0, 0);
    }

    // epilogue: C/D layout col=lane&15, row=(lane>>4)*4+reg (gfx950-verified)
    const int ecol = lane & 15;
    const int q4   = (lane >> 4) * 4;
    #pragma unroll
    for (int m = 0; m < 4; ++m) {
        #pragma unroll
        for (int n = 0; n < 4; ++n) {
            const int gcol = colBase + wc + n * 16 + ecol;
            #pragma unroll
            for (int r = 0; r < 4; ++r) {
                const int grow = rowBase + wr + m * 16 + q4 + r;
                float v = acc[m][n][r];
                if (EPI == 0) {
                    ((half_t*)Cv)[z * bsC + (long long)grow * ldc + gcol] = (half_t)v;
                } else if (EPI == 1) {
                    ((float*)Cv)[(long long)grow * ldc + gcol] = v + bias[gcol];
                } else {
                    // QKV routing: block-uniform on colBase
                    const int mat = colBase >> 10;      // 0=q, 1=k, 2=v
                    const int c   = gcol & 1023;
                    if (mat == 0) {
                        ((half_t*)Cv)[(long long)grow * 1024 + c] = (half_t)(v * 0.03125f);
                    } else if (mat == 1) {
                        ((half_t*)C2)[(long long)grow * 1024 + c] = (half_t)v;
                    } else {
                        // vT[b][c][t], b=grow>>11, t=grow&2047
                        const long long bb = grow >> 11;
                        const long long tt = grow & 2047;
                        ((half_t*)C3)[bb * (1024LL * 2048) + (long long)c * 2048 + tt] = (half_t)v;
                    }
                }
            }
        }
    }
}

// fp32 -> fp16 flat cast, 8 elems/thread
__global__ __launch_bounds__(256)
void cast16(const float* __restrict__ x, half_t* __restrict__ y)
{
    const long long i = ((long long)blockIdx.x * 256 + threadIdx.x) * 8;
    floatx4 a = *(const floatx4*)(x + i);
    floatx4 b = *(const floatx4*)(x + i + 4);
    half8 h;
    #pragma unroll
    for (int j = 0; j < 4; ++j) { h[j] = (half_t)a[j]; h[j + 4] = (half_t)b[j]; }
    *(half8*)(y + i) = h;
}

// 1024x1024 fp32 -> fp16 transposed; grid.z selects which weight
__global__ __launch_bounds__(256)
void cast_transpose4(const float* __restrict__ W0, const float* __restrict__ W1,
                     const float* __restrict__ W2, const float* __restrict__ W3,
                     half_t* __restrict__ WT)
{
    const float* W = (blockIdx.z == 0) ? W0 : (blockIdx.z == 1) ? W1
                   : (blockIdx.z == 2) ? W2 : W3;
    half_t* O = WT + (long long)blockIdx.z * 1024 * 1024;
    __shared__ float t[32][33];
    const int bx = blockIdx.x * 32, by = blockIdx.y * 32;
    const int tx = threadIdx.x, ty = threadIdx.y;
    #pragma unroll
    for (int i = 0; i < 32; i += 8)
        t[ty + i][tx] = W[(long long)(by + ty + i) * 1024 + bx + tx];
    __syncthreads();
    #pragma unroll
    for (int i = 0; i < 32; i += 8)
        O[(long long)(bx + ty + i) * 1024 + by + tx] = (half_t)t[tx][ty + i];
}

// in-place fp16 row softmax over 2048; one 256-thr block per row; half8 I/O
__global__ __launch_bounds__(256)
void softmax_rows(half_t* __restrict__ S)
{
    const long long base = (long long)blockIdx.x * 2048;
    const int t = threadIdx.x;
    half8 h = *(const half8*)(S + base + t * 8);
    float v[8];
    #pragma unroll
    for (int i = 0; i < 8; ++i) v[i] = (float)h[i];
    float m = -3.0e38f;
    #pragma unroll
    for (int i = 0; i < 8; ++i) m = fmaxf(m, v[i]);
    #pragma unroll
    for (int off = 32; off > 0; off >>= 1) m = fmaxf(m, __shfl_down(m, off));
    __shared__ float redm[4], reds[4];
    const int lane = t & 63, wid = t >> 6;
    if (lane == 0) redm[wid] = m;
    __syncthreads();
    const float M = fmaxf(fmaxf(redm[0], redm[1]), fmaxf(redm[2], redm[3]));
    float s = 0.f;
    #pragma unroll
    for (int i = 0; i < 8; ++i) { v[i] = __expf(v[i] - M); s += v[i]; }
    #pragma unroll
    for (int off = 32; off > 0; off >>= 1) s += __shfl_down(s, off);
    if (lane == 0) reds[wid] = s;
    __syncthreads();
    const float inv = 1.0f / (reds[0] + reds[1] + reds[2] + reds[3]);
    #pragma unroll
    for (int i = 0; i < 8; ++i) h[i] = (half_t)(v[i] * inv);
    *(half8*)(S + base + t * 8) = h;
}

extern "C" void kernel_launch(void* const* d_in, const int* in_sizes, int n_in,
                              void* d_out, int out_size, void* d_ws, size_t ws_size,
                              hipStream_t stream)
{
    const float* x  = (const float*)d_in[0];
    const float* Wq = (const float*)d_in[1];
    const float* Wk = (const float*)d_in[2];
    const float* Wv = (const float*)d_in[3];
    const float* Wp = (const float*)d_in[4];
    const float* bp = (const float*)d_in[5];
    float* out = (float*)d_out;

    char* ws = (char*)d_ws;
    const long long MB = 1024LL * 1024LL;
    half_t* WqkvT = (half_t*)(ws + 0 * MB);   // [3072][1024] = WqT|WkT|WvT
    half_t* WpT   = (half_t*)(ws + 6 * MB);
    half_t* q     = (half_t*)(ws + 8 * MB);   // [8][2048][1024]; later ctx
    half_t* k     = (half_t*)(ws + 40 * MB);
    half_t* vT    = (half_t*)(ws + 72 * MB);  // [8][1024][2048]
    half_t* x16   = (half_t*)(ws + 104 * MB); // dead after QKV
    half_t* S     = (half_t*)(ws + 104 * MB); // [8][2048][2048] fp16, overlays x16

    dim3 blk(256);
    cast16<<<8192, blk, 0, stream>>>(x, x16);
    cast_transpose4<<<dim3(32, 32, 4), dim3(32, 8), 0, stream>>>(Wq, Wk, Wv, Wp, WqkvT);

    // fused QKV: [16384,1024] @ [3072,1024]^T, routed epilogue. 3072 blocks.
    gemm16<2><<<dim3(24, 128, 1), blk, 0, stream>>>(
        x16, WqkvT, q, k, vT, nullptr, 1024, 1024, 1024, 0, 0, 0, 0);

    // S = q @ k^T (fp16 out), all 8 batches. 2048 blocks.
    gemm16<0><<<dim3(16, 16, 8), blk, 0, stream>>>(
        q, k, S, nullptr, nullptr, nullptr, 1024, 1024, 1024, 2048,
        2048LL * 1024, 2048LL * 1024, 2048LL * 2048);

    // P = softmax(S) in place
    softmax_rows<<<8 * 2048, blk, 0, stream>>>(S);

    // ctx = P @ vT^T (fp16), overwrites q. 1024 blocks.
    gemm16<0><<<dim3(8, 16, 8), blk, 0, stream>>>(
        S, vT, q, nullptr, nullptr, nullptr, 2048, 2048, 2048, 1024,
        2048LL * 2048, 1024LL * 2048, 2048LL * 1024);

    // out = ctx @ WpT^T + bp (fp32). 1024 blocks.
    gemm16<1><<<dim3(8, 128, 1), blk, 0, stream>>>(
        q, WpT, out, nullptr, nullptr, bp, 1024, 1024, 1024, 1024, 0, 0, 0);
}

// Round 4
// 549.455 us; speedup vs baseline: 1.4635x; 1.0101x over previous
//
#include <hip/hip_runtime.h>

// MiniSelfAttention: B=8, T=2048, D=1024, fp32 in/out, fp16 MFMA internally.
// R4: pipelined K-loop — double-buffered LDS, raw s_barrier, manual
// s_waitcnt vmcnt(0) AFTER the MFMA block so the next tile's global_load_lds
// DMA overlaps compute (removes __syncthreads' pre-barrier vmcnt(0) drain).
//
// ws layout (MB):
//   [0,6)    WqkvT = WqT|WkT|WvT contiguous (fp16 [3072][1024])
//   [6,8)    WpT fp16
//   [8,40)   q fp16 [8][2048][1024]   (later overwritten by ctx)
//   [40,72)  k fp16
//   [72,104) vT fp16 [8][1024][2048]
//   [104,136) x16 fp16 (dead after QKV), overlaid by:
//   [104,168) S fp16 [8][2048][2048]  (softmaxed in place -> P)

typedef _Float16 half_t;
typedef _Float16 half8 __attribute__((ext_vector_type(8)));
typedef float floatx4 __attribute__((ext_vector_type(4)));

// async global->LDS, 16B per lane; LDS dest = wave-uniform base + lane*16
#define GLD16(gp, lp)                                                          \
    __builtin_amdgcn_global_load_lds(                                          \
        (const __attribute__((address_space(1))) void*)(gp),                   \
        (__attribute__((address_space(3))) void*)(lp), 16, 0, 0)

#define WAIT_VM0()  asm volatile("s_waitcnt vmcnt(0)" ::: "memory")
#define BARRIER()   do { asm volatile("" ::: "memory");                        \
                         __builtin_amdgcn_s_barrier();                         \
                         asm volatile("" ::: "memory"); } while (0)

// ---------------------------------------------------------------------------
// fp16 NT GEMM: 128x128 tile, BK=32, 4 waves, 4x4 16x16x32 frags,
// double-buffered LDS + raw-barrier pipeline (1 barrier/iter, drain after MFMA)
// EPI: 0 = fp16 C store; 1 = fp32 C + bias; 2 = QKV-routed (q*1/32, k, vT)
// ---------------------------------------------------------------------------
template<int EPI>
__global__ __launch_bounds__(256, 2)
void gemm16(const half_t* __restrict__ A, const half_t* __restrict__ B,
            void* __restrict__ Cv, void* __restrict__ C2, void* __restrict__ C3,
            const float* __restrict__ bias, int K, int lda, int ldb, int ldc,
            long long bsA, long long bsB, long long bsC)
{
    __shared__ half_t As[2 * 128 * 32];  // unpadded (global_load_lds), 2 buffers
    __shared__ half_t Bs[2 * 128 * 32];

    const int tid  = threadIdx.x;
    const int lane = tid & 63;
    const int wid  = tid >> 6;
    const int wr   = (wid >> 1) * 64;
    const int wc   = (wid & 1) * 64;
    const long long z = blockIdx.z;
    const int rowBase = blockIdx.y * 128;
    const int colBase = blockIdx.x * 128;

    // staging: wave w stages tile rows [w*32, w*32+32) of A and B,
    // two 1KB global_load_lds each (16 rows x 64B per instruction)
    const int srow = wid * 32 + (lane >> 2);
    const int scol = (lane & 3) * 8;

    const half_t* ga0 = A + z * bsA + (long long)(rowBase + srow) * lda + scol;
    const half_t* ga1 = ga0 + 16LL * lda;
    const half_t* gb0 = B + z * bsB + (long long)(colBase + srow) * ldb + scol;
    const half_t* gb1 = gb0 + 16LL * ldb;
    const int lso0 = (wid * 32) * 32;        // wave-uniform LDS offsets
    const int lso1 = (wid * 32 + 16) * 32;

    floatx4 acc[4][4];
    #pragma unroll
    for (int m = 0; m < 4; ++m)
        #pragma unroll
        for (int n = 0; n < 4; ++n)
            #pragma unroll
            for (int j = 0; j < 4; ++j) acc[m][n][j] = 0.0f;

    const int fr = lane & 15;
    const int fk = (lane >> 4) * 8;
    const int nIter = K >> 5;

    // prolog: stage tile 0 into buffer 0
    GLD16(ga0, &As[lso0]);
    GLD16(ga1, &As[lso1]);
    GLD16(gb0, &Bs[lso0]);
    GLD16(gb1, &Bs[lso1]);
    WAIT_VM0();
    BARRIER();

    for (int it = 0; it < nIter; ++it) {
        const int cur = (it & 1) * 4096;
        const int nxt = 4096 - cur;
        // prefetch tile it+1 into the other buffer (DMA flies during MFMA)
        if (it + 1 < nIter) {
            const int kk = (it + 1) << 5;
            GLD16(ga0 + kk, &As[nxt + lso0]);
            GLD16(ga1 + kk, &As[nxt + lso1]);
            GLD16(gb0 + kk, &Bs[nxt + lso0]);
            GLD16(gb1 + kk, &Bs[nxt + lso1]);
        }

        half8 af[4], bf[4];
        #pragma unroll
        for (int m = 0; m < 4; ++m)
            af[m] = *(const half8*)&As[cur + (wr + m * 16 + fr) * 32 + fk];
        #pragma unroll
        for (int n = 0; n < 4; ++n)
            bf[n] = *(const half8*)&Bs[cur + (wc + n * 16 + fr) * 32 + fk];
        #pragma unroll
        for (int m = 0; m < 4; ++m)
            #pragma unroll
            for (int n = 0; n < 4; ++n)
                acc[m][n] = __builtin_amdgcn_mfma_f32_16x16x32_f16(af[m], bf[n], acc[m][n], 0, 0, 0);

        // drain own prefetch DMAs (hidden behind the MFMA above), then publish
        WAIT_VM0();
        BARRIER();
    }

    // epilogue: C/D layout col=lane&15, row=(lane>>4)*4+reg (gfx950-verified)
    const int ecol = lane & 15;
    const int q4   = (lane >> 4) * 4;
    #pragma unroll
    for (int m = 0; m < 4; ++m) {
        #pragma unroll
        for (int n = 0; n < 4; ++n) {
            const int gcol = colBase + wc + n * 16 + ecol;
            #pragma unroll
            for (int r = 0; r < 4; ++r) {
                const int grow = rowBase + wr + m * 16 + q4 + r;
                float v = acc[m][n][r];
                if (EPI == 0) {
                    ((half_t*)Cv)[z * bsC + (long long)grow * ldc + gcol] = (half_t)v;
                } else if (EPI == 1) {
                    ((float*)Cv)[(long long)grow * ldc + gcol] = v + bias[gcol];
                } else {
                    // QKV routing: block-uniform on colBase
                    const int mat = colBase >> 10;      // 0=q, 1=k, 2=v
                    const int c   = gcol & 1023;
                    if (mat == 0) {
                        ((half_t*)Cv)[(long long)grow * 1024 + c] = (half_t)(v * 0.03125f);
                    } else if (mat == 1) {
                        ((half_t*)C2)[(long long)grow * 1024 + c] = (half_t)v;
                    } else {
                        // vT[b][c][t], b=grow>>11, t=grow&2047
                        const long long bb = grow >> 11;
                        const long long tt = grow & 2047;
                        ((half_t*)C3)[bb * (1024LL * 2048) + (long long)c * 2048 + tt] = (half_t)v;
                    }
                }
            }
        }
    }
}

// fp32 -> fp16 flat cast, 8 elems/thread
__global__ __launch_bounds__(256)
void cast16(const float* __restrict__ x, half_t* __restrict__ y)
{
    const long long i = ((long long)blockIdx.x * 256 + threadIdx.x) * 8;
    floatx4 a = *(const floatx4*)(x + i);
    floatx4 b = *(const floatx4*)(x + i + 4);
    half8 h;
    #pragma unroll
    for (int j = 0; j < 4; ++j) { h[j] = (half_t)a[j]; h[j + 4] = (half_t)b[j]; }
    *(half8*)(y + i) = h;
}

// 1024x1024 fp32 -> fp16 transposed; grid.z selects which weight
__global__ __launch_bounds__(256)
void cast_transpose4(const float* __restrict__ W0, const float* __restrict__ W1,
                     const float* __restrict__ W2, const float* __restrict__ W3,
                     half_t* __restrict__ WT)
{
    const float* W = (blockIdx.z == 0) ? W0 : (blockIdx.z == 1) ? W1
                   : (blockIdx.z == 2) ? W2 : W3;
    half_t* O = WT + (long long)blockIdx.z * 1024 * 1024;
    __shared__ float t[32][33];
    const int bx = blockIdx.x * 32, by = blockIdx.y * 32;
    const int tx = threadIdx.x, ty = threadIdx.y;
    #pragma unroll
    for (int i = 0; i < 32; i += 8)
        t[ty + i][tx] = W[(long long)(by + ty + i) * 1024 + bx + tx];
    __syncthreads();
    #pragma unroll
    for (int i = 0; i < 32; i += 8)
        O[(long long)(bx + ty + i) * 1024 + by + tx] = (half_t)t[tx][ty + i];
}

// in-place fp16 row softmax over 2048; one 256-thr block per row; half8 I/O
__global__ __launch_bounds__(256)
void softmax_rows(half_t* __restrict__ S)
{
    const long long base = (long long)blockIdx.x * 2048;
    const int t = threadIdx.x;
    half8 h = *(const half8*)(S + base + t * 8);
    float v[8];
    #pragma unroll
    for (int i = 0; i < 8; ++i) v[i] = (float)h[i];
    float m = -3.0e38f;
    #pragma unroll
    for (int i = 0; i < 8; ++i) m = fmaxf(m, v[i]);
    #pragma unroll
    for (int off = 32; off > 0; off >>= 1) m = fmaxf(m, __shfl_down(m, off));
    __shared__ float redm[4], reds[4];
    const int lane = t & 63, wid = t >> 6;
    if (lane == 0) redm[wid] = m;
    __syncthreads();
    const float M = fmaxf(fmaxf(redm[0], redm[1]), fmaxf(redm[2], redm[3]));
    float s = 0.f;
    #pragma unroll
    for (int i = 0; i < 8; ++i) { v[i] = __expf(v[i] - M); s += v[i]; }
    #pragma unroll
    for (int off = 32; off > 0; off >>= 1) s += __shfl_down(s, off);
    if (lane == 0) reds[wid] = s;
    __syncthreads();
    const float inv = 1.0f / (reds[0] + reds[1] + reds[2] + reds[3]);
    #pragma unroll
    for (int i = 0; i < 8; ++i) h[i] = (half_t)(v[i] * inv);
    *(half8*)(S + base + t * 8) = h;
}

extern "C" void kernel_launch(void* const* d_in, const int* in_sizes, int n_in,
                              void* d_out, int out_size, void* d_ws, size_t ws_size,
                              hipStream_t stream)
{
    const float* x  = (const float*)d_in[0];
    const float* Wq = (const float*)d_in[1];
    const float* Wk = (const float*)d_in[2];
    const float* Wv = (const float*)d_in[3];
    const float* Wp = (const float*)d_in[4];
    const float* bp = (const float*)d_in[5];
    float* out = (float*)d_out;

    char* ws = (char*)d_ws;
    const long long MB = 1024LL * 1024LL;
    half_t* WqkvT = (half_t*)(ws + 0 * MB);   // [3072][1024] = WqT|WkT|WvT
    half_t* WpT   = (half_t*)(ws + 6 * MB);
    half_t* q     = (half_t*)(ws + 8 * MB);   // [8][2048][1024]; later ctx
    half_t* k     = (half_t*)(ws + 40 * MB);
    half_t* vT    = (half_t*)(ws + 72 * MB);  // [8][1024][2048]
    half_t* x16   = (half_t*)(ws + 104 * MB); // dead after QKV
    half_t* S     = (half_t*)(ws + 104 * MB); // [8][2048][2048] fp16, overlays x16

    dim3 blk(256);
    cast16<<<8192, blk, 0, stream>>>(x, x16);
    cast_transpose4<<<dim3(32, 32, 4), dim3(32, 8), 0, stream>>>(Wq, Wk, Wv, Wp, WqkvT);

    // fused QKV: [16384,1024] @ [3072,1024]^T, routed epilogue. 3072 blocks.
    gemm16<2><<<dim3(24, 128, 1), blk, 0, stream>>>(
        x16, WqkvT, q, k, vT, nullptr, 1024, 1024, 1024, 0, 0, 0, 0);

    // S = q @ k^T (fp16 out), all 8 batches. 2048 blocks.
    gemm16<0><<<dim3(16, 16, 8), blk, 0, stream>>>(
        q, k, S, nullptr, nullptr, nullptr, 1024, 1024, 1024, 2048,
        2048LL * 1024, 2048LL * 1024, 2048LL * 2048);

    // P = softmax(S) in place
    softmax_rows<<<8 * 2048, blk, 0, stream>>>(S);

    // ctx = P @ vT^T (fp16), overwrites q. 1024 blocks.
    gemm16<0><<<dim3(8, 16, 8), blk, 0, stream>>>(
        S, vT, q, nullptr, nullptr, nullptr, 2048, 2048, 2048, 1024,
        2048LL * 2048, 1024LL * 2048, 2048LL * 1024);

    // out = ctx @ WpT^T + bp (fp32). 1024 blocks.
    gemm16<1><<<dim3(8, 128, 1), blk, 0, stream>>>(
        q, WpT, out, nullptr, nullptr, bp, 1024, 1024, 1024, 1024, 0, 0, 0);
}